// Round 5
// baseline (461.213 us; speedup 1.0000x reference)
//
#include <hip/hip_runtime.h>
#include <hip/hip_fp16.h>

#define TLEN 512
#define HDIM 32
#define FOUT 20
#define HST  36   // h row stride in halfwords (72B = 18 dwords; gcd(18,32)=2 -> conflict-free, measured r0/r1/r4)

typedef __attribute__((ext_vector_type(8))) short bf16x8;
typedef __attribute__((ext_vector_type(4))) float f32x4;
typedef __attribute__((ext_vector_type(4))) short s16x4;

__device__ __forceinline__ float sigm(float v) {
  float e = __builtin_amdgcn_exp2f(-1.4426950408889634f * v);
  return __builtin_amdgcn_rcpf(1.0f + e);
}
__device__ __forceinline__ float tanh_f(float v) {
  float e = __builtin_amdgcn_exp2f(2.8853900817779268f * v);
  return 1.0f - 2.0f * __builtin_amdgcn_rcpf(1.0f + e);
}
// round-to-nearest-even bf16 hi/lo split: v ~= hi + lo (~16-bit mantissa coverage)
__device__ __forceinline__ void hilo(float v, short& h, short& l) {
  unsigned u = __builtin_bit_cast(unsigned, v);
  unsigned r = u + 0x7fffu + ((u >> 16) & 1u);
  h = (short)(r >> 16);
  float hf = __builtin_bit_cast(float, r & 0xffff0000u);
  float res = v - hf;
  unsigned u2 = __builtin_bit_cast(unsigned, res);
  unsigned r2 = u2 + 0x7fffu + ((u2 >> 16) & 1u);
  l = (short)(r2 >> 16);
}

// Barrier draining only LDS (lgkmcnt) — global output stores keep flowing.
__device__ __forceinline__ void barrier_lgkm() {
  asm volatile("s_waitcnt lgkmcnt(0)\n\ts_barrier" ::: "memory");
}

// two adjacent 8B reads -> one bf16x8 fragment (conflict-free at stride 36)
__device__ __forceinline__ bf16x8 read_h(const short* buf, int off) {
  s16x4 a = *(const s16x4*)(buf + off);
  s16x4 b = *(const s16x4*)(buf + off + 4);
  bf16x8 r;
  r[0]=a[0]; r[1]=a[1]; r[2]=a[2]; r[3]=a[3];
  r[4]=b[0]; r[5]=b[1]; r[6]=b[2]; r[7]=b[3];
  return r;
}

// gates in regs: g[0..3] = i,f,g,o for ONE (batch,unit) position
__device__ __forceinline__ float lstm_update(const f32x4& g, float& c) {
  float iv = sigm(g[0]), fv = sigm(g[1]), gv = tanh_f(g[2]), ov = sigm(g[3]);
  c = fv * c + iv * gv;
  return ov * tanh_f(c);
}

// Block: 1024 threads = 16 waves, 16 batch rows, all T. 256 blocks = 1/CU.
//   waves 0-7  = L1 (computes h1(T) at iter T)
//   waves 8-15 = L2 (computes h2(T-2) at iter T; lag 2)
//   out-proj emits s=T-3 (lag 3), rotated across L1 wave-pairs.
// DEEP PIPELINE (vs r4's lag-1): ring-4 LDS h-buffers + parity-double-buffered
// h1 registers on L2 waves. Only the two self-recurrences (h1->h1 on L1 waves,
// h2->h2 on L2 waves) read one-barrier-fresh; L2's h1 input is read a FULL step
// before use, and the duty pair's h2 is read a full step before emit. Post-barrier,
// L2's Wih2@h1 MFMAs are immediately issuable (h1 already in regs), covering the
// L1 waves' fresh-read latency; arithmetic is bit-identical to r3/r4.
__global__ __launch_bounds__(1024, 1) void lstm_seq_kernel(
    const float* __restrict__ xg,
    const float* __restrict__ Wih1, const float* __restrict__ Whh1,
    const float* __restrict__ bih1, const float* __restrict__ bhh1,
    const float* __restrict__ Wih2, const float* __restrict__ Whh2,
    const float* __restrict__ bih2, const float* __restrict__ bhh2,
    const float* __restrict__ Wout, const float* __restrict__ bout,
    float* __restrict__ out)
{
  __shared__ __half xl[16 * 1028];                          // x staged fp16
  __shared__ short h1hiB[4][16 * HST], h1loB[4][16 * HST];  // ring-4 h buffers
  __shared__ short h2hiB[4][16 * HST], h2loB[4][16 * HST];

  const int tid  = threadIdx.x;
  const int w    = tid >> 6;     // wave 0..15
  const int lane = tid & 63;
  const int n    = lane & 15;    // A-row (weights) / B-col & C-col (batch) / update batch
  const int q    = lane >> 4;    // quad
  const int q4   = q * 4;
  const int q8   = q * 8;
  const int b0   = blockIdx.x * 16;
  const bool isL1 = (w < 8);
  const int wr   = w & 7;        // role-local tile index 0..7
  const int p    = w & 1;        // out-proj tile (cols 16p..16p+15), L1 waves only
  const int pr   = w >> 1;       // out-proj duty pair id 0..3, L1 waves only

  // ---- stage x[b0..b0+15][0..1024) into LDS as fp16 (coalesced)
  for (int idx = tid; idx < 16 * 1024; idx += 1024) {
    int row = idx >> 10, col = idx & 1023;
    xl[row * 1028 + col] = __float2half(xg[((size_t)(b0 + row) << 10) + col]);
  }

  // ---- weight A-fragments: A[m=lane&15][k=q8+j]; row m -> gate m&3, unit 4wr+(m>>2)
  const int og = (n & 3) * HDIM + 4 * wr + (n >> 2);
  bf16x8 WAh, WAl, WBh, WBl;   // L1: WA=Whh1 (WB unused). L2: WA=Wih2, WB=Whh2
  float bc[4], wx0[4], wx1[4], boc[4];
  bf16x8 WoH = {0,0,0,0,0,0,0,0}, WoL = {0,0,0,0,0,0,0,0};
  if (isL1) {
    #pragma unroll
    for (int j = 0; j < 8; j++) {
      short hh, ll;
      hilo(Whh1[og * HDIM + q8 + j], hh, ll); WAh[j] = hh; WAl[j] = ll;
    }
    #pragma unroll
    for (int r = 0; r < 4; r++) {
      int gr = r * HDIM + 4 * wr + q;
      bc[r]  = bih1[gr] + bhh1[gr];
      wx0[r] = Wih1[gr * 2 + 0];
      wx1[r] = Wih1[gr * 2 + 1];
      int orow = 16 * p + q4 + r;
      boc[r] = (orow < FOUT) ? bout[orow] : 0.0f;
    }
    int orow = 16 * p + n;
    if (orow < FOUT) {
      #pragma unroll
      for (int j = 0; j < 8; j++) {
        short hh, ll;
        hilo(Wout[orow * HDIM + q8 + j], hh, ll); WoH[j] = hh; WoL[j] = ll;
      }
    }
  } else {
    #pragma unroll
    for (int j = 0; j < 8; j++) {
      short hh, ll;
      hilo(Wih2[og * HDIM + q8 + j], hh, ll); WAh[j] = hh; WAl[j] = ll;
      hilo(Whh2[og * HDIM + q8 + j], hh, ll); WBh[j] = hh; WBl[j] = ll;
    }
    #pragma unroll
    for (int r = 0; r < 4; r++) {
      int gr = r * HDIM + 4 * wr + q;
      bc[r] = bih2[gr] + bhh2[gr];
    }
  }

  const int hoff = n * HST + 4 * wr + q;  // write: (batch n, unit 4wr+q)
  const int aoff = n * HST + q8;          // B-frag read: h[batch n][k=q8..q8+7]
  float c = 0.0f;                         // c1 on L1 waves, c2 on L2 waves

  // h1h/h1l: L1's running h1(T-1); on L2 waves: parity-0 h1 set (holds h1(even))
  // h1nh/h1nl: L2's parity-1 h1 set (holds h1(odd))
  bf16x8 h1h = {0,0,0,0,0,0,0,0}, h1l = {0,0,0,0,0,0,0,0};
  bf16x8 h1nh = {0,0,0,0,0,0,0,0}, h1nl = {0,0,0,0,0,0,0,0};
  bf16x8 h2h = {0,0,0,0,0,0,0,0}, h2l = {0,0,0,0,0,0,0,0};

  __syncthreads();   // x staging visible (full barrier once)

  // ================= T = 0: L1 only (h1(-1)=0 -> pure VALU, no MFMA)
  if (isL1) {
    __half2 hv = *(const __half2*)&xl[n * 1028];
    float xv0 = __half2float(hv.x), xv1 = __half2float(hv.y);
    f32x4 g1;
    #pragma unroll
    for (int r = 0; r < 4; r++) g1[r] = fmaf(xv1, wx1[r], fmaf(xv0, wx0[r], bc[r]));
    float h1n = lstm_update(g1, c);
    short hh, ll; hilo(h1n, hh, ll);
    h1hiB[0][hoff] = hh; h1loB[0][hoff] = ll;
  }
  barrier_lgkm();
  // all waves pick up h1(0) into set0 (L1: next-step input; L2: for s=0 at T=2)
  h1h = read_h(h1hiB[0], aoff);
  h1l = read_h(h1loB[0], aoff);

  // ===== STEP macro: iter T. Slots S0=T&3, S1=(T-1)&3, S2=(T-2)&3, S3=(T-3)&3.
  // L1 computes h1(T) -> h1B[S0]. L2 computes s=T-2 using H1X (=h1(T-2), read at
  // iter T-2) and h2 regs (=h2(T-3), read at iter T-1) -> h2B[S2].
  // Post-barrier: L1 reads fresh h1B[S0]; pair pr==S2 reads fresh h2B[S2];
  // pair pr==S3 emits s_o=T-3 (regs read at iter T-1). L2 reads h1B[S0] into H1X
  // (used at T+2: parity-matched) and h2B[S2] (used at T+1).
#define STEP(S0,S1,S2,S3, TOUT, H1X, H1XL, L1C, L2C, L2H1R, L2H2R, PREAD, EMIT, XV0, XV1) \
  {                                                                               \
    if (isL1) {                                                                   \
      if (L1C) {                                                                  \
        f32x4 g1;                                                                 \
        _Pragma("unroll") for (int r = 0; r < 4; r++)                             \
          g1[r] = fmaf((XV1), wx1[r], fmaf((XV0), wx0[r], bc[r]));                \
        g1 = __builtin_amdgcn_mfma_f32_16x16x32_bf16(WAh, h1h, g1, 0, 0, 0);      \
        g1 = __builtin_amdgcn_mfma_f32_16x16x32_bf16(WAl, h1h, g1, 0, 0, 0);      \
        g1 = __builtin_amdgcn_mfma_f32_16x16x32_bf16(WAh, h1l, g1, 0, 0, 0);      \
        float h1n = lstm_update(g1, c);                                           \
        short hh, ll; hilo(h1n, hh, ll);                                          \
        h1hiB[S0][hoff] = hh; h1loB[S0][hoff] = ll;                               \
      }                                                                           \
    } else {                                                                      \
      if (L2C) {                                                                  \
        f32x4 ga, gb;                                                             \
        _Pragma("unroll") for (int r = 0; r < 4; r++) { ga[r] = bc[r]; gb[r] = 0.0f; } \
        ga = __builtin_amdgcn_mfma_f32_16x16x32_bf16(WAh, H1X, ga, 0, 0, 0);      \
        gb = __builtin_amdgcn_mfma_f32_16x16x32_bf16(WBh, h2h, gb, 0, 0, 0);      \
        ga = __builtin_amdgcn_mfma_f32_16x16x32_bf16(WAl, H1X, ga, 0, 0, 0);      \
        gb = __builtin_amdgcn_mfma_f32_16x16x32_bf16(WBl, h2h, gb, 0, 0, 0);      \
        ga = __builtin_amdgcn_mfma_f32_16x16x32_bf16(WAh, H1XL, ga, 0, 0, 0);     \
        gb = __builtin_amdgcn_mfma_f32_16x16x32_bf16(WBh, h2l, gb, 0, 0, 0);      \
        f32x4 g2;                                                                 \
        _Pragma("unroll") for (int r = 0; r < 4; r++) g2[r] = ga[r] + gb[r];      \
        float h2n = lstm_update(g2, c);                                           \
        short hh, ll; hilo(h2n, hh, ll);                                          \
        h2hiB[S2][hoff] = hh; h2loB[S2][hoff] = ll;                               \
      }                                                                           \
    }                                                                             \
    barrier_lgkm();                                                               \
    if (isL1) {                                                                   \
      if (L1C) {                                                                  \
        h1h = read_h(h1hiB[S0], aoff);                                            \
        h1l = read_h(h1loB[S0], aoff);                                            \
      }                                                                           \
      if ((PREAD) && pr == (S2)) {                                                \
        h2h = read_h(h2hiB[S2], aoff);                                            \
        h2l = read_h(h2loB[S2], aoff);                                            \
      }                                                                           \
      if ((EMIT) && pr == (S3)) {                                                 \
        f32x4 ao;                                                                 \
        _Pragma("unroll") for (int r = 0; r < 4; r++) ao[r] = boc[r];             \
        ao = __builtin_amdgcn_mfma_f32_16x16x32_bf16(WoH, h2h, ao, 0, 0, 0);      \
        ao = __builtin_amdgcn_mfma_f32_16x16x32_bf16(WoL, h2h, ao, 0, 0, 0);      \
        ao = __builtin_amdgcn_mfma_f32_16x16x32_bf16(WoH, h2l, ao, 0, 0, 0);      \
        if (p == 0 || q == 0) {                                                   \
          float4 st = { ao[0], ao[1], ao[2], ao[3] };                             \
          *(float4*)&out[((size_t)(b0 + n) * TLEN + (TOUT)) * FOUT + 16 * p + q4] = st; \
        }                                                                         \
      }                                                                           \
    } else {                                                                      \
      if (L2H1R) {                                                                \
        H1X  = read_h(h1hiB[S0], aoff);                                           \
        H1XL = read_h(h1loB[S0], aoff);                                           \
      }                                                                           \
      if (L2H2R) {                                                                \
        h2h = read_h(h2hiB[S2], aoff);                                            \
        h2l = read_h(h2loB[S2], aoff);                                            \
      }                                                                           \
    }                                                                             \
  }

  // ================= peel: T = 1, 2, 3
  {
    float a0 = 0.f, a1 = 0.f;
    if (isL1) { __half2 hv = *(const __half2*)&xl[n * 1028 + 2]; a0 = __half2float(hv.x); a1 = __half2float(hv.y); }
    STEP(1,0,3,2, 0, h1nh,h1nl, 1,0,1,0,0,0, a0, a1);   // L2 picks up h1(1) -> set1
    if (isL1) { __half2 hv = *(const __half2*)&xl[n * 1028 + 4]; a0 = __half2float(hv.x); a1 = __half2float(hv.y); }
    STEP(2,1,0,3, 0, h1h,h1l,   1,1,1,1,1,0, a0, a1);   // L2: s=0 (h2 regs = 0)
    if (isL1) { __half2 hv = *(const __half2*)&xl[n * 1028 + 6]; a0 = __half2float(hv.x); a1 = __half2float(hv.y); }
    STEP(3,2,1,0, 0, h1nh,h1nl, 1,1,1,1,1,1, a0, a1);   // L2: s=1; pair0 emits s_o=0
  }

  // ================= main: 4x unrolled, T = 4..511 (127 groups)
  for (int t = 4; t < TLEN; t += 4) {
    float xv[8] = {0.f, 0.f, 0.f, 0.f, 0.f, 0.f, 0.f, 0.f};
    if (isL1) {
      const short* xp = (const short*)xl + n * 1028 + 2 * t;   // 8B-aligned
      s16x4 xa = *(const s16x4*)xp;
      s16x4 xb = *(const s16x4*)(xp + 4);
      #pragma unroll
      for (int j = 0; j < 4; j++) {
        xv[j]     = __half2float(__builtin_bit_cast(__half, (short)xa[j]));
        xv[4 + j] = __half2float(__builtin_bit_cast(__half, (short)xb[j]));
      }
    }
    STEP(0,3,2,1, t - 3, h1h,h1l,   1,1,1,1,1,1, xv[0], xv[1]);
    STEP(1,0,3,2, t - 2, h1nh,h1nl, 1,1,1,1,1,1, xv[2], xv[3]);
    STEP(2,1,0,3, t - 1, h1h,h1l,   1,1,1,1,1,1, xv[4], xv[5]);
    STEP(3,2,1,0, t,     h1nh,h1nl, 1,1,1,1,1,1, xv[6], xv[7]);
  }
#undef STEP

  // ================= tails (redefine minimal step via same macro shape)
#define STEP2(S0,S1,S2,S3, TOUT, H1X, H1XL, L2C, L2H2R, PREAD, EMIT)              \
  {                                                                               \
    if (!isL1 && (L2C)) {                                                         \
      f32x4 ga, gb;                                                               \
      _Pragma("unroll") for (int r = 0; r < 4; r++) { ga[r] = bc[r]; gb[r] = 0.0f; } \
      ga = __builtin_amdgcn_mfma_f32_16x16x32_bf16(WAh, H1X, ga, 0, 0, 0);        \
      gb = __builtin_amdgcn_mfma_f32_16x16x32_bf16(WBh, h2h, gb, 0, 0, 0);        \
      ga = __builtin_amdgcn_mfma_f32_16x16x32_bf16(WAl, H1X, ga, 0, 0, 0);        \
      gb = __builtin_amdgcn_mfma_f32_16x16x32_bf16(WBl, h2h, gb, 0, 0, 0);        \
      ga = __builtin_amdgcn_mfma_f32_16x16x32_bf16(WAh, H1XL, ga, 0, 0, 0);       \
      gb = __builtin_amdgcn_mfma_f32_16x16x32_bf16(WBh, h2l, gb, 0, 0, 0);        \
      f32x4 g2;                                                                   \
      _Pragma("unroll") for (int r = 0; r < 4; r++) g2[r] = ga[r] + gb[r];        \
      float h2n = lstm_update(g2, c);                                             \
      short hh, ll; hilo(h2n, hh, ll);                                            \
      h2hiB[S2][hoff] = hh; h2loB[S2][hoff] = ll;                                 \
    }                                                                             \
    barrier_lgkm();                                                               \
    if (isL1) {                                                                   \
      if ((PREAD) && pr == (S2)) {                                                \
        h2h = read_h(h2hiB[S2], aoff);                                            \
        h2l = read_h(h2loB[S2], aoff);                                            \
      }                                                                           \
      if ((EMIT) && pr == (S3)) {                                                 \
        f32x4 ao;                                                                 \
        _Pragma("unroll") for (int r = 0; r < 4; r++) ao[r] = boc[r];             \
        ao = __builtin_amdgcn_mfma_f32_16x16x32_bf16(WoH, h2h, ao, 0, 0, 0);      \
        ao = __builtin_amdgcn_mfma_f32_16x16x32_bf16(WoL, h2h, ao, 0, 0, 0);      \
        ao = __builtin_amdgcn_mfma_f32_16x16x32_bf16(WoH, h2l, ao, 0, 0, 0);      \
        if (p == 0 || q == 0) {                                                   \
          float4 st = { ao[0], ao[1], ao[2], ao[3] };                             \
          *(float4*)&out[((size_t)(b0 + n) * TLEN + (TOUT)) * FOUT + 16 * p + q4] = st; \
        }                                                                         \
      }                                                                           \
    } else {                                                                      \
      if (L2H2R) {                                                                \
        h2h = read_h(h2hiB[S2], aoff);                                            \
        h2l = read_h(h2loB[S2], aoff);                                            \
      }                                                                           \
    }                                                                             \
  }

  // T=512: L2 s=510 (uses h1(510)=set0, h2(509)); pair1 emits s_o=509; pair2 reads h2(510)
  STEP2(0,3,2,1, TLEN - 3, h1h,h1l, 1, 1, 1, 1);
  // T=513: L2 s=511 (uses h1(511)=set1, h2(510)); pair2 emits s_o=510; pair3 reads h2(511)
  STEP2(1,0,3,2, TLEN - 2, h1nh,h1nl, 1, 0, 1, 1);
#undef STEP2

  // final: pair 3 emits s_o=511 (h2(511) in regs, read at T=513)
  if (isL1 && pr == 3) {
    const int s = TLEN - 1;
    f32x4 ao;
    #pragma unroll
    for (int r = 0; r < 4; r++) ao[r] = boc[r];
    ao = __builtin_amdgcn_mfma_f32_16x16x32_bf16(WoH, h2h, ao, 0, 0, 0);
    ao = __builtin_amdgcn_mfma_f32_16x16x32_bf16(WoL, h2h, ao, 0, 0, 0);
    ao = __builtin_amdgcn_mfma_f32_16x16x32_bf16(WoH, h2l, ao, 0, 0, 0);
    if (p == 0 || q == 0) {
      float4 st = { ao[0], ao[1], ao[2], ao[3] };
      *(float4*)&out[((size_t)(b0 + n) * TLEN + s) * FOUT + 16 * p + q4] = st;
    }
  }
}

extern "C" void kernel_launch(void* const* d_in, const int* in_sizes, int n_in,
                              void* d_out, int out_size, void* d_ws, size_t ws_size,
                              hipStream_t stream) {
  const float* xg   = (const float*)d_in[0];
  const float* Wih1 = (const float*)d_in[1];
  const float* Whh1 = (const float*)d_in[2];
  const float* bih1 = (const float*)d_in[3];
  const float* bhh1 = (const float*)d_in[4];
  const float* Wih2 = (const float*)d_in[5];
  const float* Whh2 = (const float*)d_in[6];
  const float* bih2 = (const float*)d_in[7];
  const float* bhh2 = (const float*)d_in[8];
  const float* Wout = (const float*)d_in[9];
  const float* bout = (const float*)d_in[10];
  float* out = (float*)d_out;

  hipLaunchKernelGGL(lstm_seq_kernel, dim3(256), dim3(1024), 0, stream,
                     xg, Wih1, Whh1, bih1, bhh1, Wih2, Whh2, bih2, bhh2, Wout, bout, out);
}

// Round 6
// 440.450 us; speedup vs baseline: 1.0471x; 1.0471x over previous
//
#include <hip/hip_runtime.h>
#include <hip/hip_fp16.h>

#define TLEN 512
#define HDIM 32
#define FOUT 20
#define HST  40   // 80B rows: 16B-aligned b128 frags. 4-way conflicts (3.5e7) but HIDDEN:
                  // r3 (b128+conflicts) 327.5us beat r4 (2xb64 conflict-free) 338.8us.

typedef __attribute__((ext_vector_type(8))) short bf16x8;
typedef __attribute__((ext_vector_type(4))) float f32x4;
typedef __attribute__((ext_vector_type(4))) short s16x4;

__device__ __forceinline__ float sigm(float v) {
  float e = __builtin_amdgcn_exp2f(-1.4426950408889634f * v);
  return __builtin_amdgcn_rcpf(1.0f + e);
}
__device__ __forceinline__ float tanh_f(float v) {
  float e = __builtin_amdgcn_exp2f(2.8853900817779268f * v);
  return 1.0f - 2.0f * __builtin_amdgcn_rcpf(1.0f + e);
}
// round-to-nearest-even bf16 hi/lo split: v ~= hi + lo (~16-bit mantissa coverage)
__device__ __forceinline__ void hilo(float v, short& h, short& l) {
  unsigned u = __builtin_bit_cast(unsigned, v);
  unsigned r = u + 0x7fffu + ((u >> 16) & 1u);
  h = (short)(r >> 16);
  float hf = __builtin_bit_cast(float, r & 0xffff0000u);
  float res = v - hf;
  unsigned u2 = __builtin_bit_cast(unsigned, res);
  unsigned r2 = u2 + 0x7fffu + ((u2 >> 16) & 1u);
  l = (short)(r2 >> 16);
}

// Barrier draining only LDS (lgkmcnt) — global output stores keep flowing.
// NOTE: the lgkmcnt(0) drain means every read issued in step T completes before
// step T+1 begins — post-barrier reads are "free" prefetches for the next step.
__device__ __forceinline__ void barrier_lgkm() {
  asm volatile("s_waitcnt lgkmcnt(0)\n\ts_barrier" ::: "memory");
}

// one 16B-aligned ds_read_b128 -> one bf16x8 fragment
__device__ __forceinline__ bf16x8 read_h(const short* buf, int off) {
  return *(const bf16x8*)(buf + off);
}

// gates in regs: g[0..3] = i,f,g,o for ONE (batch,unit) position
__device__ __forceinline__ float lstm_update(const f32x4& g, float& c) {
  float iv = sigm(g[0]), fv = sigm(g[1]), gv = tanh_f(g[2]), ov = sigm(g[3]);
  c = fv * c + iv * gv;
  return ov * tanh_f(c);
}

// Block: 1024 threads = 16 waves, 16 batch rows, all T. 256 blocks = 1/CU.
//   waves 0-7  = L1: 3 MFMA + x-FMA + h1 update + (rotated) out-proj
//   waves 8-15 = L2: 6 MFMA + h2 update
// Pipeline at iter t: L1 computes h1(t), L2 computes h2(t-1), out-proj emits s=t-2
// (duty wave-pair pr==(s&3), tile p=w&1; duty waves pre-read h2(s) the iter before).
// 4x unrolled, compile-time slots; out-proj after the barrier in the read shadow.
// This round: accumulator inits folded into MFMA C-inputs (bcv/zv4/bocv) — pure
// issue-count reduction, bit-identical arithmetic.
__global__ __launch_bounds__(1024, 1) void lstm_seq_kernel(
    const float* __restrict__ xg,
    const float* __restrict__ Wih1, const float* __restrict__ Whh1,
    const float* __restrict__ bih1, const float* __restrict__ bhh1,
    const float* __restrict__ Wih2, const float* __restrict__ Whh2,
    const float* __restrict__ bih2, const float* __restrict__ bhh2,
    const float* __restrict__ Wout, const float* __restrict__ bout,
    float* __restrict__ out)
{
  __shared__ __half xl[16 * 1028];                  // x staged fp16
  __shared__ short h1hiB[2][16 * HST], h1loB[2][16 * HST];  // ping-pong h buffers
  __shared__ short h2hiB[2][16 * HST], h2loB[2][16 * HST];

  const int tid  = threadIdx.x;
  const int w    = tid >> 6;     // wave 0..15
  const int lane = tid & 63;
  const int n    = lane & 15;    // A-row (weights) / B-col & C-col (batch) / update batch
  const int q    = lane >> 4;    // quad
  const int q4   = q * 4;
  const int q8   = q * 8;
  const int b0   = blockIdx.x * 16;
  const bool isL1 = (w < 8);
  const int wr   = w & 7;        // role-local tile index 0..7
  const int p    = w & 1;        // out-proj tile (cols 16p..16p+15), L1 waves only
  const int pr   = w >> 1;       // out-proj duty pair id 0..3, L1 waves only

  // ---- stage x[b0..b0+15][0..1024) into LDS as fp16 (coalesced)
  for (int idx = tid; idx < 16 * 1024; idx += 1024) {
    int row = idx >> 10, col = idx & 1023;
    xl[row * 1028 + col] = __float2half(xg[((size_t)(b0 + row) << 10) + col]);
  }

  // ---- weight A-fragments: A[m=lane&15][k=q8+j]; row m -> gate m&3, unit 4wr+(m>>2)
  const int og = (n & 3) * HDIM + 4 * wr + (n >> 2);
  bf16x8 WAh, WAl, WBh, WBl;   // L1: WA=Whh1 (WB unused). L2: WA=Wih2, WB=Whh2
  float bc[4], wx0[4], wx1[4];
  f32x4 bcv = {0.f, 0.f, 0.f, 0.f};        // L2: b2 as MFMA C-input
  f32x4 bocv = {0.f, 0.f, 0.f, 0.f};       // L1: bout as out-proj C-input
  const f32x4 zv4 = {0.f, 0.f, 0.f, 0.f};  // zero C-input for gb chain
  bf16x8 WoH = {0,0,0,0,0,0,0,0}, WoL = {0,0,0,0,0,0,0,0};
  if (isL1) {
    #pragma unroll
    for (int j = 0; j < 8; j++) {
      short hh, ll;
      hilo(Whh1[og * HDIM + q8 + j], hh, ll); WAh[j] = hh; WAl[j] = ll;
    }
    // per-reg constants for the lane's update position (batch n, unit 4wr+q), gate r
    #pragma unroll
    for (int r = 0; r < 4; r++) {
      int gr = r * HDIM + 4 * wr + q;
      bc[r]  = bih1[gr] + bhh1[gr];
      wx0[r] = Wih1[gr * 2 + 0];
      wx1[r] = Wih1[gr * 2 + 1];
      int orow = 16 * p + q4 + r;
      bocv[r] = (orow < FOUT) ? bout[orow] : 0.0f;
    }
    // out-proj A-frag: row m -> out-row 16p+m (zero-padded past 19)
    int orow = 16 * p + n;
    if (orow < FOUT) {
      #pragma unroll
      for (int j = 0; j < 8; j++) {
        short hh, ll;
        hilo(Wout[orow * HDIM + q8 + j], hh, ll); WoH[j] = hh; WoL[j] = ll;
      }
    }
  } else {
    #pragma unroll
    for (int j = 0; j < 8; j++) {
      short hh, ll;
      hilo(Wih2[og * HDIM + q8 + j], hh, ll); WAh[j] = hh; WAl[j] = ll;
      hilo(Whh2[og * HDIM + q8 + j], hh, ll); WBh[j] = hh; WBl[j] = ll;
    }
    #pragma unroll
    for (int r = 0; r < 4; r++) {
      int gr = r * HDIM + 4 * wr + q;
      bcv[r] = bih2[gr] + bhh2[gr];
      bc[r]  = bcv[r];
    }
  }

  const int hoff = n * HST + 4 * wr + q;  // write: (batch n, unit 4wr+q)
  const int aoff = n * HST + q8;          // B-frag read: h[batch n][k=q8..q8+7] (16B aligned)
  float c = 0.0f;                         // c1 on L1 waves, c2 on L2 waves

  bf16x8 h1h = {0,0,0,0,0,0,0,0}, h1l = {0,0,0,0,0,0,0,0};
  bf16x8 h2h = {0,0,0,0,0,0,0,0}, h2l = {0,0,0,0,0,0,0,0};

  __syncthreads();   // x staging visible (full barrier once)

  // ================= head: t = 0 (L1 only; h1(-1)=0 -> pure VALU, no MFMA)
  if (isL1) {
    __half2 hv = *(const __half2*)&xl[n * 1028];
    float xv0 = __half2float(hv.x), xv1 = __half2float(hv.y);
    f32x4 g1;
    #pragma unroll
    for (int r = 0; r < 4; r++) g1[r] = fmaf(xv1, wx1[r], fmaf(xv0, wx0[r], bc[r]));
    float h1n = lstm_update(g1, c);
    short hh, ll; hilo(h1n, hh, ll);
    h1hiB[0][hoff] = hh; h1loB[0][hoff] = ll;
  }
  barrier_lgkm();
  h1h = read_h(h1hiB[0], aoff);
  h1l = read_h(h1loB[0], aoff);
  // (no h2 read at head: h2(-1)=0 already in regs for L2; duty s<0 never uses h2)

  // ================= STEP macro: iter T computes L1(T) / L2(T-1); PAR=T&1;
  // DS3 = (T-2)&3 duty slot (or -1); HR3 = (T-1)&3 h2-read slot. All compile-time.
#define STEP(T, PAR, DS3, HR3, XV0, XV1)                                          \
  {                                                                               \
    if (isL1) {                                                                   \
      f32x4 g1;                                                                   \
      _Pragma("unroll") for (int r = 0; r < 4; r++)                               \
        g1[r] = fmaf((XV1), wx1[r], fmaf((XV0), wx0[r], bc[r]));                  \
      g1 = __builtin_amdgcn_mfma_f32_16x16x32_bf16(WAh, h1h, g1, 0, 0, 0);        \
      g1 = __builtin_amdgcn_mfma_f32_16x16x32_bf16(WAl, h1h, g1, 0, 0, 0);        \
      g1 = __builtin_amdgcn_mfma_f32_16x16x32_bf16(WAh, h1l, g1, 0, 0, 0);        \
      float h1n = lstm_update(g1, c);                                             \
      short hh, ll; hilo(h1n, hh, ll);                                            \
      h1hiB[PAR][hoff] = hh; h1loB[PAR][hoff] = ll;                               \
    } else {                                                                      \
      f32x4 ga = __builtin_amdgcn_mfma_f32_16x16x32_bf16(WAh, h1h, bcv, 0, 0, 0); \
      f32x4 gb = __builtin_amdgcn_mfma_f32_16x16x32_bf16(WBh, h2h, zv4, 0, 0, 0); \
      ga = __builtin_amdgcn_mfma_f32_16x16x32_bf16(WAl, h1h, ga, 0, 0, 0);        \
      gb = __builtin_amdgcn_mfma_f32_16x16x32_bf16(WBl, h2h, gb, 0, 0, 0);        \
      ga = __builtin_amdgcn_mfma_f32_16x16x32_bf16(WAh, h1l, ga, 0, 0, 0);        \
      gb = __builtin_amdgcn_mfma_f32_16x16x32_bf16(WBh, h2l, gb, 0, 0, 0);        \
      f32x4 g2;                                                                   \
      _Pragma("unroll") for (int r = 0; r < 4; r++) g2[r] = ga[r] + gb[r];        \
      float h2n = lstm_update(g2, c);                                             \
      short hh, ll; hilo(h2n, hh, ll);                                            \
      h2hiB[PAR][hoff] = hh; h2loB[PAR][hoff] = ll;                               \
    }                                                                             \
    barrier_lgkm();   /* h1(T), h2(T-1) visible */                                \
    h1h = read_h(h1hiB[PAR], aoff);                                               \
    h1l = read_h(h1loB[PAR], aoff);                                               \
    /* out-proj s=T-2 in the ds_read latency shadow (old h2 regs survive barrier; \
       duty slot DS3 != read slot HR3, so no per-wave conflict) */                \
    if ((DS3) >= 0 && isL1 && pr == (DS3)) {                                      \
      f32x4 ao = __builtin_amdgcn_mfma_f32_16x16x32_bf16(WoH, h2h, bocv, 0, 0, 0);\
      ao = __builtin_amdgcn_mfma_f32_16x16x32_bf16(WoL, h2h, ao, 0, 0, 0);        \
      ao = __builtin_amdgcn_mfma_f32_16x16x32_bf16(WoH, h2l, ao, 0, 0, 0);        \
      if (p == 0 || q == 0) {                                                     \
        float4 st = { ao[0], ao[1], ao[2], ao[3] };                               \
        *(float4*)&out[((size_t)(b0 + n) * TLEN + ((T) - 2)) * FOUT + 16 * p + q4] = st; \
      }                                                                           \
    }                                                                             \
    if (!isL1 || pr == (HR3)) {                                                   \
      h2h = read_h(h2hiB[PAR], aoff);                                             \
      h2l = read_h(h2loB[PAR], aoff);                                             \
    }                                                                             \
  }

  // ================= peel: t = 1, 2, 3 (compile-time constants)
  {
    float a0 = 0.f, a1 = 0.f;
    if (isL1) { __half2 hv = *(const __half2*)&xl[n * 1028 + 2]; a0 = __half2float(hv.x); a1 = __half2float(hv.y); }
    STEP(1, 1, -1, 0, a0, a1);
    if (isL1) { __half2 hv = *(const __half2*)&xl[n * 1028 + 4]; a0 = __half2float(hv.x); a1 = __half2float(hv.y); }
    STEP(2, 0, 0, 1, a0, a1);
    if (isL1) { __half2 hv = *(const __half2*)&xl[n * 1028 + 6]; a0 = __half2float(hv.x); a1 = __half2float(hv.y); }
    STEP(3, 1, 1, 2, a0, a1);
  }

  // ================= main: 4x unrolled, t = 4..511 (127 groups)
  float xv[8] = {0.f, 0.f, 0.f, 0.f, 0.f, 0.f, 0.f, 0.f};
  for (int t = 4; t < TLEN; t += 4) {
    if (isL1) {
      const short* xp = (const short*)xl + n * 1028 + 2 * t;   // 8B-aligned
      s16x4 xa = *(const s16x4*)xp;
      s16x4 xb = *(const s16x4*)(xp + 4);
      #pragma unroll
      for (int j = 0; j < 4; j++) {
        xv[j]     = __half2float(__builtin_bit_cast(__half, (short)xa[j]));
        xv[4 + j] = __half2float(__builtin_bit_cast(__half, (short)xb[j]));
      }
    }
    STEP(t + 0, 0, 2, 3, xv[0], xv[1]);
    STEP(t + 1, 1, 3, 0, xv[2], xv[3]);
    STEP(t + 2, 0, 0, 1, xv[4], xv[5]);
    STEP(t + 3, 1, 1, 2, xv[6], xv[7]);
  }
#undef STEP

  // ================= epilogue E1: L2 computes h2(511); duty pair 2 emits s=510
  if (!isL1) {
    f32x4 ga = __builtin_amdgcn_mfma_f32_16x16x32_bf16(WAh, h1h, bcv, 0, 0, 0);
    f32x4 gb = __builtin_amdgcn_mfma_f32_16x16x32_bf16(WBh, h2h, zv4, 0, 0, 0);
    ga = __builtin_amdgcn_mfma_f32_16x16x32_bf16(WAl, h1h, ga, 0, 0, 0);
    gb = __builtin_amdgcn_mfma_f32_16x16x32_bf16(WBl, h2h, gb, 0, 0, 0);
    ga = __builtin_amdgcn_mfma_f32_16x16x32_bf16(WAh, h1l, ga, 0, 0, 0);
    gb = __builtin_amdgcn_mfma_f32_16x16x32_bf16(WBh, h2l, gb, 0, 0, 0);
    f32x4 g2;
    #pragma unroll
    for (int r = 0; r < 4; r++) g2[r] = ga[r] + gb[r];
    float h2n = lstm_update(g2, c);
    short hh, ll; hilo(h2n, hh, ll);
    h2hiB[0][hoff] = hh; h2loB[0][hoff] = ll;
  } else if (pr == 2) {              // s = 510, 510&3 == 2
    const int s = TLEN - 2;
    f32x4 ao = __builtin_amdgcn_mfma_f32_16x16x32_bf16(WoH, h2h, bocv, 0, 0, 0);
    ao = __builtin_amdgcn_mfma_f32_16x16x32_bf16(WoL, h2h, ao, 0, 0, 0);
    ao = __builtin_amdgcn_mfma_f32_16x16x32_bf16(WoH, h2l, ao, 0, 0, 0);
    if (p == 0 || q == 0) {
      float4 st = { ao[0], ao[1], ao[2], ao[3] };
      *(float4*)&out[((size_t)(b0 + n) * TLEN + s) * FOUT + 16 * p + q4] = st;
    }
  }
  barrier_lgkm();

  // ================= epilogue E2: duty pair 3 emits s=511 with fresh h2(511)
  if (isL1 && pr == 3) {             // s = 511, 511&3 == 3
    h2h = read_h(h2hiB[0], aoff);
    h2l = read_h(h2loB[0], aoff);
    const int s = TLEN - 1;
    f32x4 ao = __builtin_amdgcn_mfma_f32_16x16x32_bf16(WoH, h2h, bocv, 0, 0, 0);
    ao = __builtin_amdgcn_mfma_f32_16x16x32_bf16(WoL, h2h, ao, 0, 0, 0);
    ao = __builtin_amdgcn_mfma_f32_16x16x32_bf16(WoH, h2l, ao, 0, 0, 0);
    if (p == 0 || q == 0) {
      float4 st = { ao[0], ao[1], ao[2], ao[3] };
      *(float4*)&out[((size_t)(b0 + n) * TLEN + s) * FOUT + 16 * p + q4] = st;
    }
  }
}

extern "C" void kernel_launch(void* const* d_in, const int* in_sizes, int n_in,
                              void* d_out, int out_size, void* d_ws, size_t ws_size,
                              hipStream_t stream) {
  const float* xg   = (const float*)d_in[0];
  const float* Wih1 = (const float*)d_in[1];
  const float* Whh1 = (const float*)d_in[2];
  const float* bih1 = (const float*)d_in[3];
  const float* bhh1 = (const float*)d_in[4];
  const float* Wih2 = (const float*)d_in[5];
  const float* Whh2 = (const float*)d_in[6];
  const float* bih2 = (const float*)d_in[7];
  const float* bhh2 = (const float*)d_in[8];
  const float* Wout = (const float*)d_in[9];
  const float* bout = (const float*)d_in[10];
  float* out = (float*)d_out;

  hipLaunchKernelGGL(lstm_seq_kernel, dim3(256), dim3(1024), 0, stream,
                     xg, Wih1, Whh1, bih1, bhh1, Wih2, Whh2, bih2, bhh2, Wout, bout, out);
}

// Round 7
// 436.711 us; speedup vs baseline: 1.0561x; 1.0086x over previous
//
#include <hip/hip_runtime.h>
#include <hip/hip_fp16.h>

#define TLEN 512
#define HDIM 32
#define FOUT 20
#define HST  40   // 80B rows: 16B-aligned b128 frags. 4-way conflicts hidden (r3 beat conflict-free r4):
                  // b64 ~6cyc vs b128 ~12cyc per wave-op -> same LDS-pipe bytes/cyc either way.

typedef __attribute__((ext_vector_type(8))) short bf16x8;
typedef __attribute__((ext_vector_type(4))) float f32x4;
typedef __attribute__((ext_vector_type(4))) short s16x4;

__device__ __forceinline__ float sigm(float v) {
  float e = __builtin_amdgcn_exp2f(-1.4426950408889634f * v);
  return __builtin_amdgcn_rcpf(1.0f + e);
}
__device__ __forceinline__ float tanh_f(float v) {
  float e = __builtin_amdgcn_exp2f(2.8853900817779268f * v);
  return 1.0f - 2.0f * __builtin_amdgcn_rcpf(1.0f + e);
}
// round-to-nearest-even bf16 hi/lo split: v ~= hi + lo (~16-bit mantissa coverage)
__device__ __forceinline__ void hilo(float v, short& h, short& l) {
  unsigned u = __builtin_bit_cast(unsigned, v);
  unsigned r = u + 0x7fffu + ((u >> 16) & 1u);
  h = (short)(r >> 16);
  float hf = __builtin_bit_cast(float, r & 0xffff0000u);
  float res = v - hf;
  unsigned u2 = __builtin_bit_cast(unsigned, res);
  unsigned r2 = u2 + 0x7fffu + ((u2 >> 16) & 1u);
  l = (short)(r2 >> 16);
}

// Barrier draining only LDS (lgkmcnt) — global output stores keep flowing.
__device__ __forceinline__ void barrier_lgkm() {
  asm volatile("s_waitcnt lgkmcnt(0)\n\ts_barrier" ::: "memory");
}

// one 16B-aligned ds_read_b128 -> one bf16x8 fragment
__device__ __forceinline__ bf16x8 read_h(const short* buf, int off) {
  return *(const bf16x8*)(buf + off);
}

// gates in regs: g[0..3] = i,f,g,o for ONE (batch,unit) position
__device__ __forceinline__ float lstm_update(const f32x4& g, float& c) {
  float iv = sigm(g[0]), fv = sigm(g[1]), gv = tanh_f(g[2]), ov = sigm(g[3]);
  c = fv * c + iv * gv;
  return ov * tanh_f(c);
}

// Block: 1024 threads = 16 waves, 16 batch rows, all T. 256 blocks = 1/CU.
//   waves 0-7  = L1: x-FMA + 3 MFMA + h1 update. Nothing post-barrier but the h1 re-read.
//   waves 8-15 = L2: 6 MFMA + h2 update + OUT-PROJ DUTY (new this round).
// Out-proj moved from L1 to L2 pairs: L2 re-reads h2 every step anyway (self-recurrence),
// so at step T its pre-overwrite registers hold h2(T-2) — the duty pair (pr==(T-2)&3)
// emits s=T-2 from stale regs with ZERO extra LDS reads, filling L2's otherwise-empty
// post-barrier window. L1 sheds WoH/WoL/bocv/h2-state entirely. Bit-identical arithmetic.
__global__ __launch_bounds__(1024, 1) void lstm_seq_kernel(
    const float* __restrict__ xg,
    const float* __restrict__ Wih1, const float* __restrict__ Whh1,
    const float* __restrict__ bih1, const float* __restrict__ bhh1,
    const float* __restrict__ Wih2, const float* __restrict__ Whh2,
    const float* __restrict__ bih2, const float* __restrict__ bhh2,
    const float* __restrict__ Wout, const float* __restrict__ bout,
    float* __restrict__ out)
{
  __shared__ __half xl[16 * 1028];                  // x staged fp16
  __shared__ short h1hiB[2][16 * HST], h1loB[2][16 * HST];  // ping-pong h buffers
  __shared__ short h2hiB[2][16 * HST], h2loB[2][16 * HST];

  const int tid  = threadIdx.x;
  const int w    = tid >> 6;     // wave 0..15
  const int lane = tid & 63;
  const int n    = lane & 15;    // A-row (weights) / B-col & C-col (batch) / update batch
  const int q    = lane >> 4;    // quad
  const int q4   = q * 4;
  const int q8   = q * 8;
  const int b0   = blockIdx.x * 16;
  const bool isL1 = (w < 8);
  const int wr   = w & 7;        // role-local tile index 0..7
  const int p    = w & 1;        // out-proj tile (cols 16p..16p+15), L2 waves only
  const int pr   = (w >> 1) & 3; // out-proj duty pair id 0..3, L2 waves only

  // ---- stage x[b0..b0+15][0..1024) into LDS as fp16 (coalesced)
  for (int idx = tid; idx < 16 * 1024; idx += 1024) {
    int row = idx >> 10, col = idx & 1023;
    xl[row * 1028 + col] = __float2half(xg[((size_t)(b0 + row) << 10) + col]);
  }

  // ---- weight A-fragments: A[m=lane&15][k=q8+j]; row m -> gate m&3, unit 4wr+(m>>2)
  const int og = (n & 3) * HDIM + 4 * wr + (n >> 2);
  bf16x8 WAh, WAl, WBh, WBl;   // L1: WA=Whh1 (WB unused). L2: WA=Wih2, WB=Whh2
  float bc[4], wx0[4], wx1[4];
  f32x4 bcv = {0.f, 0.f, 0.f, 0.f};        // L2: b2 as MFMA C-input
  f32x4 bocv = {0.f, 0.f, 0.f, 0.f};       // L2: bout as out-proj C-input
  const f32x4 zv4 = {0.f, 0.f, 0.f, 0.f};  // zero C-input for gb chain
  bf16x8 WoH = {0,0,0,0,0,0,0,0}, WoL = {0,0,0,0,0,0,0,0};
  if (isL1) {
    #pragma unroll
    for (int j = 0; j < 8; j++) {
      short hh, ll;
      hilo(Whh1[og * HDIM + q8 + j], hh, ll); WAh[j] = hh; WAl[j] = ll;
    }
    // per-reg constants for the lane's update position (batch n, unit 4wr+q), gate r
    #pragma unroll
    for (int r = 0; r < 4; r++) {
      int gr = r * HDIM + 4 * wr + q;
      bc[r]  = bih1[gr] + bhh1[gr];
      wx0[r] = Wih1[gr * 2 + 0];
      wx1[r] = Wih1[gr * 2 + 1];
    }
  } else {
    #pragma unroll
    for (int j = 0; j < 8; j++) {
      short hh, ll;
      hilo(Wih2[og * HDIM + q8 + j], hh, ll); WAh[j] = hh; WAl[j] = ll;
      hilo(Whh2[og * HDIM + q8 + j], hh, ll); WBh[j] = hh; WBl[j] = ll;
    }
    #pragma unroll
    for (int r = 0; r < 4; r++) {
      int gr = r * HDIM + 4 * wr + q;
      bcv[r] = bih2[gr] + bhh2[gr];
      int orow = 16 * p + q4 + r;
      bocv[r] = (orow < FOUT) ? bout[orow] : 0.0f;
    }
    // out-proj A-frag: row m -> out-row 16p+m (zero-padded past 19)
    int orow = 16 * p + n;
    if (orow < FOUT) {
      #pragma unroll
      for (int j = 0; j < 8; j++) {
        short hh, ll;
        hilo(Wout[orow * HDIM + q8 + j], hh, ll); WoH[j] = hh; WoL[j] = ll;
      }
    }
  }

  const int hoff = n * HST + 4 * wr + q;  // write: (batch n, unit 4wr+q)
  const int aoff = n * HST + q8;          // B-frag read: h[batch n][k=q8..q8+7] (16B aligned)
  float c = 0.0f;                         // c1 on L1 waves, c2 on L2 waves

  bf16x8 h1h = {0,0,0,0,0,0,0,0}, h1l = {0,0,0,0,0,0,0,0};
  bf16x8 h2h = {0,0,0,0,0,0,0,0}, h2l = {0,0,0,0,0,0,0,0};

  __syncthreads();   // x staging visible (full barrier once)

  // ================= head: t = 0 (L1 only; h1(-1)=0 -> pure VALU, no MFMA)
  if (isL1) {
    __half2 hv = *(const __half2*)&xl[n * 1028];
    float xv0 = __half2float(hv.x), xv1 = __half2float(hv.y);
    f32x4 g1;
    #pragma unroll
    for (int r = 0; r < 4; r++) g1[r] = fmaf(xv1, wx1[r], fmaf(xv0, wx0[r], bc[r]));
    float h1n = lstm_update(g1, c);
    short hh, ll; hilo(h1n, hh, ll);
    h1hiB[0][hoff] = hh; h1loB[0][hoff] = ll;
  }
  barrier_lgkm();
  h1h = read_h(h1hiB[0], aoff);   // all waves need h1(0); L2's h2 regs = h2(-1) = 0
  h1l = read_h(h1loB[0], aoff);

  // ================= STEP macro: iter T computes L1(T) / L2(T-1); PAR=T&1;
  // DS3 = (T-2)&3 duty slot (or -1). Post-barrier: L1 reads h1(T); L2 duty pair
  // emits s=T-2 from STALE h2 regs (h2(T-2), read at T-1), then all L2 read
  // h1(T) and h2(T-1). All slots compile-time.
#define STEP(T, PAR, DS3, XV0, XV1)                                              \
  {                                                                               \
    if (isL1) {                                                                   \
      f32x4 g1;                                                                   \
      _Pragma("unroll") for (int r = 0; r < 4; r++)                               \
        g1[r] = fmaf((XV1), wx1[r], fmaf((XV0), wx0[r], bc[r]));                  \
      g1 = __builtin_amdgcn_mfma_f32_16x16x32_bf16(WAh, h1h, g1, 0, 0, 0);        \
      g1 = __builtin_amdgcn_mfma_f32_16x16x32_bf16(WAl, h1h, g1, 0, 0, 0);        \
      g1 = __builtin_amdgcn_mfma_f32_16x16x32_bf16(WAh, h1l, g1, 0, 0, 0);        \
      float h1n = lstm_update(g1, c);                                             \
      short hh, ll; hilo(h1n, hh, ll);                                            \
      h1hiB[PAR][hoff] = hh; h1loB[PAR][hoff] = ll;                               \
    } else {                                                                      \
      f32x4 ga = __builtin_amdgcn_mfma_f32_16x16x32_bf16(WAh, h1h, bcv, 0, 0, 0); \
      f32x4 gb = __builtin_amdgcn_mfma_f32_16x16x32_bf16(WBh, h2h, zv4, 0, 0, 0); \
      ga = __builtin_amdgcn_mfma_f32_16x16x32_bf16(WAl, h1h, ga, 0, 0, 0);        \
      gb = __builtin_amdgcn_mfma_f32_16x16x32_bf16(WBl, h2h, gb, 0, 0, 0);        \
      ga = __builtin_amdgcn_mfma_f32_16x16x32_bf16(WAh, h1l, ga, 0, 0, 0);        \
      gb = __builtin_amdgcn_mfma_f32_16x16x32_bf16(WBh, h2l, gb, 0, 0, 0);        \
      f32x4 g2;                                                                   \
      _Pragma("unroll") for (int r = 0; r < 4; r++) g2[r] = ga[r] + gb[r];        \
      float h2n = lstm_update(g2, c);                                             \
      short hh, ll; hilo(h2n, hh, ll);                                            \
      h2hiB[PAR][hoff] = hh; h2loB[PAR][hoff] = ll;                               \
    }                                                                             \
    barrier_lgkm();   /* h1(T), h2(T-1) visible */                                \
    if (isL1) {                                                                   \
      h1h = read_h(h1hiB[PAR], aoff);                                             \
      h1l = read_h(h1loB[PAR], aoff);                                             \
    } else {                                                                      \
      /* out-proj s=T-2 from stale regs, BEFORE the h2 re-read (WAR dep) */       \
      if ((DS3) >= 0 && pr == (DS3)) {                                            \
        f32x4 ao = __builtin_amdgcn_mfma_f32_16x16x32_bf16(WoH, h2h, bocv, 0, 0, 0);\
        ao = __builtin_amdgcn_mfma_f32_16x16x32_bf16(WoL, h2h, ao, 0, 0, 0);      \
        ao = __builtin_amdgcn_mfma_f32_16x16x32_bf16(WoH, h2l, ao, 0, 0, 0);      \
        if (p == 0 || q == 0) {                                                   \
          float4 st = { ao[0], ao[1], ao[2], ao[3] };                             \
          *(float4*)&out[((size_t)(b0 + n) * TLEN + ((T) - 2)) * FOUT + 16 * p + q4] = st; \
        }                                                                         \
      }                                                                           \
      h1h = read_h(h1hiB[PAR], aoff);                                             \
      h1l = read_h(h1loB[PAR], aoff);                                             \
      h2h = read_h(h2hiB[PAR], aoff);                                             \
      h2l = read_h(h2loB[PAR], aoff);                                             \
    }                                                                             \
  }

  // ================= peel: t = 1, 2, 3 (compile-time constants)
  {
    float a0 = 0.f, a1 = 0.f;
    if (isL1) { __half2 hv = *(const __half2*)&xl[n * 1028 + 2]; a0 = __half2float(hv.x); a1 = __half2float(hv.y); }
    STEP(1, 1, -1, a0, a1);
    if (isL1) { __half2 hv = *(const __half2*)&xl[n * 1028 + 4]; a0 = __half2float(hv.x); a1 = __half2float(hv.y); }
    STEP(2, 0, 0, a0, a1);
    if (isL1) { __half2 hv = *(const __half2*)&xl[n * 1028 + 6]; a0 = __half2float(hv.x); a1 = __half2float(hv.y); }
    STEP(3, 1, 1, a0, a1);
  }

  // ================= main: 4x unrolled, t = 4..511 (127 groups)
  float xv[8] = {0.f, 0.f, 0.f, 0.f, 0.f, 0.f, 0.f, 0.f};
  for (int t = 4; t < TLEN; t += 4) {
    if (isL1) {
      const short* xp = (const short*)xl + n * 1028 + 2 * t;   // 8B-aligned
      s16x4 xa = *(const s16x4*)xp;
      s16x4 xb = *(const s16x4*)(xp + 4);
      #pragma unroll
      for (int j = 0; j < 4; j++) {
        xv[j]     = __half2float(__builtin_bit_cast(__half, (short)xa[j]));
        xv[4 + j] = __half2float(__builtin_bit_cast(__half, (short)xb[j]));
      }
    }
    STEP(t + 0, 0, 2, xv[0], xv[1]);
    STEP(t + 1, 1, 3, xv[2], xv[3]);
    STEP(t + 2, 0, 0, xv[4], xv[5]);
    STEP(t + 3, 1, 1, xv[6], xv[7]);
  }
#undef STEP

  // ================= epilogue E1 (T=512): L2 computes h2(511)
  // (h1 regs = h1(511), h2 regs = h2(510), both read at T=511 post-barrier)
  if (!isL1) {
    f32x4 ga = __builtin_amdgcn_mfma_f32_16x16x32_bf16(WAh, h1h, bcv, 0, 0, 0);
    f32x4 gb = __builtin_amdgcn_mfma_f32_16x16x32_bf16(WBh, h2h, zv4, 0, 0, 0);
    ga = __builtin_amdgcn_mfma_f32_16x16x32_bf16(WAl, h1h, ga, 0, 0, 0);
    gb = __builtin_amdgcn_mfma_f32_16x16x32_bf16(WBl, h2h, gb, 0, 0, 0);
    ga = __builtin_amdgcn_mfma_f32_16x16x32_bf16(WAh, h1l, ga, 0, 0, 0);
    gb = __builtin_amdgcn_mfma_f32_16x16x32_bf16(WBh, h2l, gb, 0, 0, 0);
    f32x4 g2;
    #pragma unroll
    for (int r = 0; r < 4; r++) g2[r] = ga[r] + gb[r];
    float h2n = lstm_update(g2, c);
    short hh, ll; hilo(h2n, hh, ll);
    h2hiB[0][hoff] = hh; h2loB[0][hoff] = ll;
  }
  barrier_lgkm();
  if (!isL1) {
    if (pr == 2) {                  // s = 510, 510&3 == 2: stale regs = h2(510)
      const int s = TLEN - 2;
      f32x4 ao = __builtin_amdgcn_mfma_f32_16x16x32_bf16(WoH, h2h, bocv, 0, 0, 0);
      ao = __builtin_amdgcn_mfma_f32_16x16x32_bf16(WoL, h2h, ao, 0, 0, 0);
      ao = __builtin_amdgcn_mfma_f32_16x16x32_bf16(WoH, h2l, ao, 0, 0, 0);
      if (p == 0 || q == 0) {
        float4 st = { ao[0], ao[1], ao[2], ao[3] };
        *(float4*)&out[((size_t)(b0 + n) * TLEN + s) * FOUT + 16 * p + q4] = st;
      }
    }
    if (pr == 3) {                  // s = 511: read fresh h2(511) (auto-waitcnt)
      h2h = read_h(h2hiB[0], aoff);
      h2l = read_h(h2loB[0], aoff);
      const int s = TLEN - 1;
      f32x4 ao = __builtin_amdgcn_mfma_f32_16x16x32_bf16(WoH, h2h, bocv, 0, 0, 0);
      ao = __builtin_amdgcn_mfma_f32_16x16x32_bf16(WoL, h2h, ao, 0, 0, 0);
      ao = __builtin_amdgcn_mfma_f32_16x16x32_bf16(WoH, h2l, ao, 0, 0, 0);
      if (p == 0 || q == 0) {
        float4 st = { ao[0], ao[1], ao[2], ao[3] };
        *(float4*)&out[((size_t)(b0 + n) * TLEN + s) * FOUT + 16 * p + q4] = st;
      }
    }
  }
}

extern "C" void kernel_launch(void* const* d_in, const int* in_sizes, int n_in,
                              void* d_out, int out_size, void* d_ws, size_t ws_size,
                              hipStream_t stream) {
  const float* xg   = (const float*)d_in[0];
  const float* Wih1 = (const float*)d_in[1];
  const float* Whh1 = (const float*)d_in[2];
  const float* bih1 = (const float*)d_in[3];
  const float* bhh1 = (const float*)d_in[4];
  const float* Wih2 = (const float*)d_in[5];
  const float* Whh2 = (const float*)d_in[6];
  const float* bih2 = (const float*)d_in[7];
  const float* bhh2 = (const float*)d_in[8];
  const float* Wout = (const float*)d_in[9];
  const float* bout = (const float*)d_in[10];
  float* out = (float*)d_out;

  hipLaunchKernelGGL(lstm_seq_kernel, dim3(256), dim3(1024), 0, stream,
                     xg, Wih1, Whh1, bih1, bhh1, Wih2, Whh2, bih2, bhh2, Wout, bout, out);
}